// Round 9
// baseline (328.622 us; speedup 1.0000x reference)
//
#include <hip/hip_runtime.h>
#include <math.h>

#define N_NODES 100000
#define N_EDGES 800000
#define D_IN    64
#define HC      128   // H*C
#define CAP     48    // max in-degree slots (Poisson(8): P(>48) ~ 0)

#define GEMM_BLOCKS 1563                 // ceil(100000/64)
#define FUSED_BLOCKS (3 * GEMM_BLOCKS)   // bid%3==2 -> gemm, else scatter

typedef short bf16x8 __attribute__((ext_vector_type(8)));   // 8 bf16 = 4 VGPR
typedef float f32x4  __attribute__((ext_vector_type(4)));

// tanh-approx gelu (jax.nn.gelu default approximate=True)
__device__ __forceinline__ float gelu_f(float x) {
    float x3 = x * x * x;
    float y  = 0.7978845608028654f * (x + 0.044715f * x3);
    float t = 1.0f - 2.0f / (__expf(2.0f * y) + 1.0f);
    return 0.5f * x * (1.0f + t);
}

// sum across a 16-lane row via DPP row_ror (pure VALU, no ds_swizzle)
__device__ __forceinline__ float red16(float x) {
    x += __int_as_float(__builtin_amdgcn_mov_dpp(__float_as_int(x), 0x128, 0xF, 0xF, true)); // ror:8
    x += __int_as_float(__builtin_amdgcn_mov_dpp(__float_as_int(x), 0x124, 0xF, 0xF, true)); // ror:4
    x += __int_as_float(__builtin_amdgcn_mov_dpp(__float_as_int(x), 0x122, 0xF, 0xF, true)); // ror:2
    x += __int_as_float(__builtin_amdgcn_mov_dpp(__float_as_int(x), 0x121, 0xF, 0xF, true)); // ror:1
    return x;
}

// split fp32 -> bf16 hi (rne) + bf16 lo (rne of residual); x = h + l + O(2^-18 x)
__device__ __forceinline__ void bf16split(float x, unsigned short& h, unsigned short& l) {
    unsigned b  = __float_as_uint(x);
    unsigned hb = (b + 0x7FFFu + ((b >> 16) & 1u)) & 0xFFFF0000u;
    h = (unsigned short)(hb >> 16);
    float lo = x - __uint_as_float(hb);
    unsigned c = __float_as_uint(lo);
    l = (unsigned short)((c + 0x7FFFu + ((c >> 16) & 1u)) >> 16);
}

// ---------------- W prep: lane-ordered bf16 hi/lo ---------------------------
// WB3[layer][w][nt][kh][lane][8] = exactly the consumption order of wave w's
// B-fragments -> every B-frag load in the gemm is 64 lanes x contiguous 16B
// = one coalesced 1KB request.
__global__ __launch_bounds__(256) void wprep_kernel(
    const float* __restrict__ Wl, const float* __restrict__ Wr,
    unsigned short* __restrict__ WBh, unsigned short* __restrict__ WBlo) {
    int g = blockIdx.x * 256 + threadIdx.x;       // 0..32767
    int layer = g >> 14;
    int rem   = g & 16383;        // (((w*4+nt)*2+kh)*64 + lane)*8 + j
    int j    = rem & 7;
    int idx  = rem >> 3;
    int lane = idx & 63;
    int kh   = (idx >> 6) & 1;
    int nt   = (idx >> 7) & 3;
    int w    = (idx >> 9) & 3;
    int col  = w * 64 + nt * 16 + (lane & 15);    // 0..255 (128+ = Wr)
    int k    = kh * 32 + (lane >> 4) * 8 + j;
    const float* W = (col < 128) ? Wl : Wr;
    float x = W[layer * 8192 + k * HC + (col & 127)];
    unsigned short h, l;
    bf16split(x, h, l);
    WBh[g] = h; WBlo[g] = l;
}

// ---------------- fused split-bf16 MFMA GEMM (+ scatter role) ---------------
// [N,64]@[64,256]: block = 64 nodes x 256 ch, 4 waves; wave w = 64 ch
// (w<2 -> XL, else XR). 3-product split: Xh*Wh + Xl*Wh + Xh*Wl = 96 MFMA.
// All global accesses coalesced: X float4 loads, lane-ordered B loads (1KB),
// LDS-staged epilogue stores (two full 512B rows per instruction).
__global__ __launch_bounds__(256, 4) void gemm_scatter_kernel(
    const float* __restrict__ X,
    const unsigned short* __restrict__ WBh, const unsigned short* __restrict__ WBlo,
    const float* __restrict__ bl, const float* __restrict__ br,
    float* __restrict__ XL, float* __restrict__ XR,
    const int* __restrict__ edges, int* __restrict__ cnt, int* __restrict__ tbl,
    int fused) {
    __shared__ union SMem {
        struct { unsigned short XH[64 * 64]; unsigned short XLo[64 * 64]; } st;
        float CS[32 * 268];       // epilogue tile, aliases dead staging bufs
    } sm;

    const int t = threadIdx.x;
    int gid;
    if (fused) {
        const int g = blockIdx.x / 3, r = blockIdx.x % 3;
        if (r != 2) {                      // ---- scatter role ----
            const int e = (2 * g + r) * 256 + t;
            if (e < N_EDGES) {
                int s = edges[e];
                int d = edges[N_EDGES + e];
                int slot = atomicAdd(&cnt[d], 1);
                if (slot < CAP) tbl[d * CAP + slot] = s;
            }
            return;
        }
        gid = g;
    } else {
        gid = blockIdx.x;
    }
    const int n0 = gid * 64;

    // stage X -> hi/lo bf16 LDS, chunk-swizzled: elem (row,k) stored at
    // row*64 + ((k>>3 ^ (row&7))<<3) + (k&7). Coalesced global float4 reads.
    #pragma unroll
    for (int p = 0; p < 4; ++p) {
        int f   = p * 256 + t;
        int row = f >> 4, q = f & 15;     // k = 4q..4q+3
        int gn  = n0 + row;
        float4 v = make_float4(0.0f, 0.0f, 0.0f, 0.0f);
        if (gn < N_NODES) v = *(const float4*)(X + (size_t)gn * D_IN + 4 * q);
        ushort4 h, l;
        bf16split(v.x, h.x, l.x); bf16split(v.y, h.y, l.y);
        bf16split(v.z, h.z, l.z); bf16split(v.w, h.w, l.w);
        int off = row * 64 + ((((q >> 1) ^ (row & 7))) << 3) + ((q & 1) << 2);
        *(ushort4*)&sm.st.XH[off]  = h;
        *(ushort4*)&sm.st.XLo[off] = l;
    }
    __syncthreads();

    const int lane = t & 63;
    const int w    = __builtin_amdgcn_readfirstlane(t >> 6);  // wave 0..3
    const float* __restrict__ bp = (w < 2) ? bl : br;
    const int cbase = (w & 1) * 64;       // ch offset within XL/XR
    const int lc    = lane & 15;
    const int lq    = lane >> 4;          // 0..3

    // acc init = bias (C/D col = lane&15; all 4 regs share the col)
    f32x4 acc[4][4];                      // [mt][nt]
    #pragma unroll
    for (int nt = 0; nt < 4; ++nt) {
        float bv = bp[cbase + nt * 16 + lc];
        #pragma unroll
        for (int mt = 0; mt < 4; ++mt)
            acc[mt][nt] = (f32x4){bv, bv, bv, bv};
    }

    #pragma unroll
    for (int kh = 0; kh < 2; ++kh) {
        // B-frags: lane-ordered layout -> contiguous 1KB per load
        bf16x8 Bh[4], Bl[4];
        #pragma unroll
        for (int nt = 0; nt < 4; ++nt) {
            int a = (((w * 4 + nt) * 2 + kh) * 64 + lane) * 8;
            Bh[nt] = *(const bf16x8*)(WBh + a);
            Bl[nt] = *(const bf16x8*)(WBlo + a);
        }
        #pragma unroll
        for (int mt = 0; mt < 4; ++mt) {
            int row = mt * 16 + lc;
            int aoff = row * 64 + ((((kh << 2) + lq) ^ (row & 7)) << 3);
            bf16x8 Ah = *(const bf16x8*)(sm.st.XH + aoff);
            bf16x8 Al = *(const bf16x8*)(sm.st.XLo + aoff);
            #pragma unroll
            for (int nt = 0; nt < 4; ++nt)
                acc[mt][nt] = __builtin_amdgcn_mfma_f32_16x16x32_bf16(Ah, Bh[nt], acc[mt][nt], 0, 0, 0);
            #pragma unroll
            for (int nt = 0; nt < 4; ++nt)
                acc[mt][nt] = __builtin_amdgcn_mfma_f32_16x16x32_bf16(Al, Bh[nt], acc[mt][nt], 0, 0, 0);
            #pragma unroll
            for (int nt = 0; nt < 4; ++nt)
                acc[mt][nt] = __builtin_amdgcn_mfma_f32_16x16x32_bf16(Ah, Bl[nt], acc[mt][nt], 0, 0, 0);
        }
    }

    // LDS-staged epilogue: 2 chunks of 32 rows x 256 unified cols
    // (cols 0-127 = XL, 128-255 = XR; colU = w*64 + nt*16 + lc).
    #pragma unroll
    for (int c = 0; c < 2; ++c) {
        __syncthreads();                  // staging bufs / prev chunk dead
        #pragma unroll
        for (int mt2 = 0; mt2 < 2; ++mt2) {
            int mt = 2 * c + mt2;
            #pragma unroll
            for (int nt = 0; nt < 4; ++nt)
                #pragma unroll
                for (int r = 0; r < 4; ++r)
                    sm.CS[(mt2 * 16 + (lq << 2) + r) * 268 + w * 64 + nt * 16 + lc]
                        = acc[mt][nt][r];
        }
        __syncthreads();
        #pragma unroll
        for (int i = 0; i < 8; ++i) {
            int lr = i * 4 + w;           // 0..31
            int n  = n0 + c * 32 + lr;
            if (n < N_NODES) {
                float4 v4 = *(const float4*)&sm.CS[lr * 268 + 4 * lane];
                float* o = ((lane < 32) ? XL : XR) + (size_t)n * HC + (lane & 31) * 4;
                *(float4*)o = v4;         // lanes 0-31: XL row, 32-63: XR row
            }
        }
    }
}

// ---------------- aggregation: 2 NODES per wave, static deep pipeline -------
// Half-wave (32 lanes) owns one node; lane li handles channels 4li..4li+3 of
// head (lane>>4)&1. Round-8 diagnosis: VALUBusy 63% + HBM 43% = latency-bound;
// per-iter ds_bpermute (shfl w/ runtime idx) -> lgkmcnt stall, and depth-3
// gather prefetch < HBM latency. Fix: indices loaded as BROADCAST int4 chunks
// straight from tbl (no cross-lane ops at all) + fully-unrolled 12x4 static
// pipeline: consume dq[t] | gather dq[t+2] (depth-8, ~80KB in flight/CU) |
// load index chunk ic[t+4]. Loads for slots >= deg are exec-masked (no junk
// traffic); addresses AND-clamped as belt-and-braces.
__global__ __launch_bounds__(256) void aggregate_kernel(
    const float* __restrict__ XL, const float* __restrict__ XR,
    const int* __restrict__ cnt, const int* __restrict__ tbl,
    const float* __restrict__ att, const float* __restrict__ bias,
    float* __restrict__ Y, int applyGelu) {
    const int wv   = (blockIdx.x * blockDim.x + threadIdx.x) >> 6;
    const int lane = threadIdx.x & 63;
    const int v    = 2 * wv + (lane >> 5);      // node per 32-lane half
    if (v >= N_NODES) return;
    const int li = lane & 15;
    const int hc = ((lane >> 4) & 1) * 64 + 4 * li;

    // issue all prologue loads up front (deg gates the gathers; ic chunks and
    // att/self rows arrive while m0 is computed)
    int deg = cnt[v];
    const int* __restrict__ tv = tbl + v * CAP;
    int4 ic[12];
    ic[0] = *(const int4*)(tv);
    ic[1] = *(const int4*)(tv + 4);
    ic[2] = *(const int4*)(tv + 8);
    ic[3] = *(const int4*)(tv + 12);

    const float4 araw = *(const float4*)(att + hc);
    const float4 xr4  = *(const float4*)(XR + (size_t)v * HC + hc);
    const float4 xl4  = *(const float4*)(XL + (size_t)v * HC + hc);
    float4 a06, a04;                            // 0.6/0.4 * log2(e) * att
    a06.x = araw.x * 0.865617024f; a06.y = araw.y * 0.865617024f;
    a06.z = araw.z * 0.865617024f; a06.w = araw.w * 0.865617024f;
    a04.x = araw.x * 0.577078016f; a04.y = araw.y * 0.577078016f;
    a04.z = araw.z * 0.577078016f; a04.w = araw.w * 0.577078016f;

#define SCORE4(Z0, Z1, Z2, Z3, OUT)                                          \
    {                                                                        \
        float pa = (Z0) * a06.x;                                             \
        float pb = fabsf(Z0) * a04.x;                                        \
        pa = fmaf((Z1), a06.y, pa); pb = fmaf(fabsf(Z1), a04.y, pb);         \
        pa = fmaf((Z2), a06.z, pa); pb = fmaf(fabsf(Z2), a04.z, pb);         \
        pa = fmaf((Z3), a06.w, pa); pb = fmaf(fabsf(Z3), a04.w, pb);         \
        OUT = pa + pb;                                                       \
    }

    // self edge score = shift m0; contributes exp2(0)=1 and xl4
    float z0 = xl4.x + xr4.x, z1 = xl4.y + xr4.y;
    float z2 = xl4.z + xr4.z, z3 = xl4.w + xr4.w;
    float p;
    SCORE4(z0, z1, z2, z3, p)
    const float m0 = red16(p);

    float s = 1.0f;
    float ax = xl4.x, ay = xl4.y, az = xl4.z, aw = xl4.w;

    if (deg > CAP) deg = CAP;
    int dmax = deg;
    { int d2 = __shfl_xor(deg, 32); dmax = d2 > dmax ? d2 : dmax; }

    const float* __restrict__ XLh = XL + hc;
    float4 dq[12][4];

    // gather slots 4q..4q+3 of this half using index chunk ic[q]; loads are
    // exec-masked by (slot < deg) -> no requests, no faults for dead slots
#define GLD(U) (*(const float4*)(XLh + (size_t)((U) & 131071) * HC))
#define LOADQ(q)                                                             \
    {                                                                        \
        int4 uu = ic[(q)];                                                   \
        float4 t0 = make_float4(0,0,0,0), t1 = t0, t2 = t0, t3 = t0;         \
        if (4*(q) + 0 < deg) t0 = GLD(uu.x);                                 \
        if (4*(q) + 1 < deg) t1 = GLD(uu.y);                                 \
        if (4*(q) + 2 < deg) t2 = GLD(uu.z);                                 \
        if (4*(q) + 3 < deg) t3 = GLD(uu.w);                                 \
        dq[(q)][0] = t0; dq[(q)][1] = t1; dq[(q)][2] = t2; dq[(q)][3] = t3;  \
    }

#define BODY(T, J)                                                           \
    {                                                                        \
        float4 xc = dq[(T)][(J)];                                            \
        float y0 = xc.x + xr4.x, y1 = xc.y + xr4.y;                          \
        float y2 = xc.z + xr4.z, y3 = xc.w + xr4.w;                          \
        float pe;                                                            \
        SCORE4(y0, y1, y2, y3, pe)                                           \
        pe = red16(pe);                                                      \
        float w = exp2f(pe - m0);                                            \
        w = (4*(T) + (J) < deg) ? w : 0.0f;                                  \
        s += w;                                                              \
        ax = fmaf(w, xc.x, ax); ay = fmaf(w, xc.y, ay);                      \
        az = fmaf(w, xc.z, az); aw = fmaf(w, xc.w, aw);                      \
    }

    if (dmax > 0) {
        LOADQ(0)
        if (dmax > 4) LOADQ(1)
        #pragma unroll
        for (int t = 0; t < 12; ++t) {
            if (4 * t < dmax) {
                if (t + 4 < 12 && 4 * (t + 4) < dmax + 16)
                    ic[t + 4] = *(const int4*)(tv + 4 * (t + 4));
                if (t + 2 < 12 && 4 * (t + 2) < dmax)
                    LOADQ(t + 2)
                BODY(t, 0) BODY(t, 1) BODY(t, 2) BODY(t, 3)
            }
        }
    }
#undef BODY
#undef LOADQ
#undef GLD
#undef SCORE4

    float inv = 1.0f / (s + 1e-16f);
    ax *= inv; ay *= inv; az *= inv; aw *= inv;

    // mean over heads (head1 sits at lane^16 within the half)
    ax += __shfl_xor(ax, 16); ay += __shfl_xor(ay, 16);
    az += __shfl_xor(az, 16); aw += __shfl_xor(aw, 16);
    ax *= 0.5f; ay *= 0.5f; az *= 0.5f; aw *= 0.5f;

    if ((lane & 31) < 16) {
        const float4 b4 = *(const float4*)(bias + 4 * li);
        ax += b4.x; ay += b4.y; az += b4.z; aw += b4.w;
        if (applyGelu) { ax = gelu_f(ax); ay = gelu_f(ay); az = gelu_f(az); aw = gelu_f(aw); }
        *(float4*)(Y + (size_t)v * 64 + 4 * li) = make_float4(ax, ay, az, aw);
    }
}

extern "C" void kernel_launch(void* const* d_in, const int* in_sizes, int n_in,
                              void* d_out, int out_size, void* d_ws, size_t ws_size,
                              hipStream_t stream) {
    const float* X     = (const float*)d_in[0];
    const int*   edges = (const int*)d_in[1];
    const float* Wl    = (const float*)d_in[2];
    const float* bl    = (const float*)d_in[3];
    const float* Wr    = (const float*)d_in[4];
    const float* br    = (const float*)d_in[5];
    const float* att   = (const float*)d_in[6];
    const float* bias  = (const float*)d_in[7];

    char* ws = (char*)d_ws;
    float* XLb = (float*)ws;                                          // N*128 f32
    float* XRb = (float*)(ws + (size_t)N_NODES * HC * 4);             // N*128 f32
    float* Yb  = (float*)(ws + (size_t)N_NODES * HC * 8);             // N*64 f32
    int*   cnt = (int*)(ws + (size_t)N_NODES * HC * 8 + (size_t)N_NODES * 64 * 4);
    int*   tbl = cnt + N_NODES;                                       // N*CAP ints
    unsigned short* WBh  = (unsigned short*)(tbl + (size_t)N_NODES * CAP); // 64 KB
    unsigned short* WBlo = WBh + 32768;                                    // 64 KB

    hipMemsetAsync(cnt, 0, N_NODES * sizeof(int), stream);
    wprep_kernel<<<128, 256, 0, stream>>>(Wl, Wr, WBh, WBlo);

    const int agg_grid = ((N_NODES + 1) / 2 * 64 + 255) / 256;        // 2 nodes/wave

    // layer 0: gemm + scatter fused (matrix/mem pipes vs atomic pipe)
    gemm_scatter_kernel<<<FUSED_BLOCKS, 256, 0, stream>>>(
        X, WBh, WBlo, bl, br, XLb, XRb, edges, cnt, tbl, 1);
    aggregate_kernel<<<agg_grid, 256, 0, stream>>>(XLb, XRb, cnt, tbl, att, bias, Yb, 1);
    // layer 1
    gemm_scatter_kernel<<<GEMM_BLOCKS, 256, 0, stream>>>(
        Yb, WBh + 16384, WBlo + 16384, bl + 128, br + 128, XLb, XRb, edges, cnt, tbl, 0);
    aggregate_kernel<<<agg_grid, 256, 0, stream>>>(XLb, XRb, cnt, tbl, att + 128, bias + 64,
                                                   (float*)d_out, 0);
}

// Round 11
// 319.173 us; speedup vs baseline: 1.0296x; 1.0296x over previous
//
#include <hip/hip_runtime.h>
#include <math.h>

#define N_NODES 100000
#define N_EDGES 800000
#define D_IN    64
#define HC      128   // H*C
#define CAP     48    // max in-degree slots (Poisson(8): P(>48) ~ 0)

#define GEMM_BLOCKS 1563                 // ceil(100000/64)
#define FUSED_BLOCKS (3 * GEMM_BLOCKS)   // bid%3==2 -> gemm, else scatter

typedef short bf16x8 __attribute__((ext_vector_type(8)));   // 8 bf16 = 4 VGPR
typedef float f32x4  __attribute__((ext_vector_type(4)));
typedef float f32x2  __attribute__((ext_vector_type(2)));

// ---- CDNA packed fp32 (VOP3P, full rate; gfx950 has add/mul/fma ONLY — ----
// ---- v_pk_max_f32 does NOT exist (round-10 compile fail) ----------------
__device__ __forceinline__ f32x2 pk_add(f32x2 a, f32x2 b) {
    f32x2 d; asm("v_pk_add_f32 %0, %1, %2" : "=v"(d) : "v"(a), "v"(b)); return d;
}
__device__ __forceinline__ f32x2 pk_mul(f32x2 a, f32x2 b) {
    f32x2 d; asm("v_pk_mul_f32 %0, %1, %2" : "=v"(d) : "v"(a), "v"(b)); return d;
}
__device__ __forceinline__ f32x2 pk_fma(f32x2 a, f32x2 b, f32x2 c) {
    f32x2 d; asm("v_pk_fma_f32 %0, %1, %2, %3" : "=v"(d) : "v"(a), "v"(b), "v"(c)); return d;
}
// |x| per half: two full-rate v_and_b32 (no packed max on gfx950)
__device__ __forceinline__ f32x2 pk_abs(f32x2 a) {
    f32x2 d; d[0] = fabsf(a[0]); d[1] = fabsf(a[1]); return d;
}

// tanh-approx gelu (jax.nn.gelu default approximate=True)
__device__ __forceinline__ float gelu_f(float x) {
    float x3 = x * x * x;
    float y  = 0.7978845608028654f * (x + 0.044715f * x3);
    float t = 1.0f - 2.0f / (__expf(2.0f * y) + 1.0f);
    return 0.5f * x * (1.0f + t);
}

// sum across a 16-lane row via DPP row_ror (pure VALU, no ds_swizzle)
__device__ __forceinline__ float red16(float x) {
    x += __int_as_float(__builtin_amdgcn_mov_dpp(__float_as_int(x), 0x128, 0xF, 0xF, true)); // ror:8
    x += __int_as_float(__builtin_amdgcn_mov_dpp(__float_as_int(x), 0x124, 0xF, 0xF, true)); // ror:4
    x += __int_as_float(__builtin_amdgcn_mov_dpp(__float_as_int(x), 0x122, 0xF, 0xF, true)); // ror:2
    x += __int_as_float(__builtin_amdgcn_mov_dpp(__float_as_int(x), 0x121, 0xF, 0xF, true)); // ror:1
    return x;
}

// split fp32 -> bf16 hi (rne) + bf16 lo (rne of residual); x = h + l + O(2^-18 x)
__device__ __forceinline__ void bf16split(float x, unsigned short& h, unsigned short& l) {
    unsigned b  = __float_as_uint(x);
    unsigned hb = (b + 0x7FFFu + ((b >> 16) & 1u)) & 0xFFFF0000u;
    h = (unsigned short)(hb >> 16);
    float lo = x - __uint_as_float(hb);
    unsigned c = __float_as_uint(lo);
    l = (unsigned short)((c + 0x7FFFu + ((c >> 16) & 1u)) >> 16);
}

// ---------------- W prep: lane-ordered bf16 hi/lo ---------------------------
// WB3[layer][w][nt][kh][lane][8] = exactly the consumption order of wave w's
// B-fragments -> every B-frag load in the gemm is 64 lanes x contiguous 16B
// = one coalesced 1KB request.
__global__ __launch_bounds__(256) void wprep_kernel(
    const float* __restrict__ Wl, const float* __restrict__ Wr,
    unsigned short* __restrict__ WBh, unsigned short* __restrict__ WBlo) {
    int g = blockIdx.x * 256 + threadIdx.x;       // 0..32767
    int layer = g >> 14;
    int rem   = g & 16383;        // (((w*4+nt)*2+kh)*64 + lane)*8 + j
    int j    = rem & 7;
    int idx  = rem >> 3;
    int lane = idx & 63;
    int kh   = (idx >> 6) & 1;
    int nt   = (idx >> 7) & 3;
    int w    = (idx >> 9) & 3;
    int col  = w * 64 + nt * 16 + (lane & 15);    // 0..255 (128+ = Wr)
    int k    = kh * 32 + (lane >> 4) * 8 + j;
    const float* W = (col < 128) ? Wl : Wr;
    float x = W[layer * 8192 + k * HC + (col & 127)];
    unsigned short h, l;
    bf16split(x, h, l);
    WBh[g] = h; WBlo[g] = l;
}

// ---------------- fused split-bf16 MFMA GEMM (+ scatter role) ---------------
// [N,64]@[64,256]: block = 64 nodes x 256 ch, 4 waves; wave w = 64 ch
// (w<2 -> XL, else XR). 3-product split: Xh*Wh + Xl*Wh + Xh*Wl = 96 MFMA.
// All global accesses coalesced: X float4 loads, lane-ordered B loads (1KB),
// LDS-staged epilogue stores (two full 512B rows per instruction).
__global__ __launch_bounds__(256, 4) void gemm_scatter_kernel(
    const float* __restrict__ X,
    const unsigned short* __restrict__ WBh, const unsigned short* __restrict__ WBlo,
    const float* __restrict__ bl, const float* __restrict__ br,
    float* __restrict__ XL, float* __restrict__ XR,
    const int* __restrict__ edges, int* __restrict__ cnt, int* __restrict__ tbl,
    int fused) {
    __shared__ union SMem {
        struct { unsigned short XH[64 * 64]; unsigned short XLo[64 * 64]; } st;
        float CS[32 * 268];       // epilogue tile, aliases dead staging bufs
    } sm;

    const int t = threadIdx.x;
    int gid;
    if (fused) {
        const int g = blockIdx.x / 3, r = blockIdx.x % 3;
        if (r != 2) {                      // ---- scatter role ----
            const int e = (2 * g + r) * 256 + t;
            if (e < N_EDGES) {
                int s = edges[e];
                int d = edges[N_EDGES + e];
                int slot = atomicAdd(&cnt[d], 1);
                if (slot < CAP) tbl[d * CAP + slot] = s;
            }
            return;
        }
        gid = g;
    } else {
        gid = blockIdx.x;
    }
    const int n0 = gid * 64;

    // stage X -> hi/lo bf16 LDS, chunk-swizzled: elem (row,k) stored at
    // row*64 + ((k>>3 ^ (row&7))<<3) + (k&7). Coalesced global float4 reads.
    #pragma unroll
    for (int p = 0; p < 4; ++p) {
        int f   = p * 256 + t;
        int row = f >> 4, q = f & 15;     // k = 4q..4q+3
        int gn  = n0 + row;
        float4 v = make_float4(0.0f, 0.0f, 0.0f, 0.0f);
        if (gn < N_NODES) v = *(const float4*)(X + (size_t)gn * D_IN + 4 * q);
        ushort4 h, l;
        bf16split(v.x, h.x, l.x); bf16split(v.y, h.y, l.y);
        bf16split(v.z, h.z, l.z); bf16split(v.w, h.w, l.w);
        int off = row * 64 + ((((q >> 1) ^ (row & 7))) << 3) + ((q & 1) << 2);
        *(ushort4*)&sm.st.XH[off]  = h;
        *(ushort4*)&sm.st.XLo[off] = l;
    }
    __syncthreads();

    const int lane = t & 63;
    const int w    = __builtin_amdgcn_readfirstlane(t >> 6);  // wave 0..3
    const float* __restrict__ bp = (w < 2) ? bl : br;
    const int cbase = (w & 1) * 64;       // ch offset within XL/XR
    const int lc    = lane & 15;
    const int lq    = lane >> 4;          // 0..3

    // acc init = bias (C/D col = lane&15; all 4 regs share the col)
    f32x4 acc[4][4];                      // [mt][nt]
    #pragma unroll
    for (int nt = 0; nt < 4; ++nt) {
        float bv = bp[cbase + nt * 16 + lc];
        #pragma unroll
        for (int mt = 0; mt < 4; ++mt)
            acc[mt][nt] = (f32x4){bv, bv, bv, bv};
    }

    #pragma unroll
    for (int kh = 0; kh < 2; ++kh) {
        // B-frags: lane-ordered layout -> contiguous 1KB per load
        bf16x8 Bh[4], Bl[4];
        #pragma unroll
        for (int nt = 0; nt < 4; ++nt) {
            int a = (((w * 4 + nt) * 2 + kh) * 64 + lane) * 8;
            Bh[nt] = *(const bf16x8*)(WBh + a);
            Bl[nt] = *(const bf16x8*)(WBlo + a);
        }
        #pragma unroll
        for (int mt = 0; mt < 4; ++mt) {
            int row = mt * 16 + lc;
            int aoff = row * 64 + ((((kh << 2) + lq) ^ (row & 7)) << 3);
            bf16x8 Ah = *(const bf16x8*)(sm.st.XH + aoff);
            bf16x8 Al = *(const bf16x8*)(sm.st.XLo + aoff);
            #pragma unroll
            for (int nt = 0; nt < 4; ++nt)
                acc[mt][nt] = __builtin_amdgcn_mfma_f32_16x16x32_bf16(Ah, Bh[nt], acc[mt][nt], 0, 0, 0);
            #pragma unroll
            for (int nt = 0; nt < 4; ++nt)
                acc[mt][nt] = __builtin_amdgcn_mfma_f32_16x16x32_bf16(Al, Bh[nt], acc[mt][nt], 0, 0, 0);
            #pragma unroll
            for (int nt = 0; nt < 4; ++nt)
                acc[mt][nt] = __builtin_amdgcn_mfma_f32_16x16x32_bf16(Ah, Bl[nt], acc[mt][nt], 0, 0, 0);
        }
    }

    // LDS-staged epilogue: 2 chunks of 32 rows x 256 unified cols
    // (cols 0-127 = XL, 128-255 = XR; colU = w*64 + nt*16 + lc).
    #pragma unroll
    for (int c = 0; c < 2; ++c) {
        __syncthreads();                  // staging bufs / prev chunk dead
        #pragma unroll
        for (int mt2 = 0; mt2 < 2; ++mt2) {
            int mt = 2 * c + mt2;
            #pragma unroll
            for (int nt = 0; nt < 4; ++nt)
                #pragma unroll
                for (int r = 0; r < 4; ++r)
                    sm.CS[(mt2 * 16 + (lq << 2) + r) * 268 + w * 64 + nt * 16 + lc]
                        = acc[mt][nt][r];
        }
        __syncthreads();
        #pragma unroll
        for (int i = 0; i < 8; ++i) {
            int lr = i * 4 + w;           // 0..31
            int n  = n0 + c * 32 + lr;
            if (n < N_NODES) {
                float4 v4 = *(const float4*)&sm.CS[lr * 268 + 4 * lane];
                float* o = ((lane < 32) ? XL : XR) + (size_t)n * HC + (lane & 31) * 4;
                *(float4*)o = v4;         // lanes 0-31: XL row, 32-63: XR row
            }
        }
    }
}

// ---------------- aggregation: 2 NODES per wave (round-8 structure) ---------
// Half-wave owns one node; lane li = channels 4li..4li+3 of head (lane>>4)&1.
// Rolling depth-3 window (VGPR ~32, occ 70% — round-9's static pipeline
// halved occupancy, reverted). Packed fp32 (v_pk_add/mul/fma; NO pk_max on
// gfx950) + abs-form leaky-relu: score = sum (0.6*l2e*att)z + (0.4*l2e*att)|z|
// -> ~24 VALU instr/edge vs 29 scalar, on a VALU-issue-bound kernel (63%).
__global__ __launch_bounds__(256) void aggregate_kernel(
    const float* __restrict__ XL, const float* __restrict__ XR,
    const int* __restrict__ cnt, const int* __restrict__ tbl,
    const float* __restrict__ att, const float* __restrict__ bias,
    float* __restrict__ Y, int applyGelu) {
    const int wv   = (blockIdx.x * blockDim.x + threadIdx.x) >> 6;
    const int lane = threadIdx.x & 63;
    const int v    = 2 * wv + (lane >> 5);      // node per 32-lane half
    if (v >= N_NODES) return;
    const int li = lane & 15;
    const int hc = ((lane >> 4) & 1) * 64 + 4 * li;
    const int selbase = lane & 32;              // shfl source base for my half

    const float4 araw = *(const float4*)(att + hc);
    const float4 xr4  = *(const float4*)(XR + (size_t)v * HC + hc);
    const float4 xl4  = *(const float4*)(XL + (size_t)v * HC + hc);

    // 0.6/0.4 * log2(e) * att, packed
    const f32x2 a06_01 = {araw.x * 0.865617024f, araw.y * 0.865617024f};
    const f32x2 a06_23 = {araw.z * 0.865617024f, araw.w * 0.865617024f};
    const f32x2 a04_01 = {araw.x * 0.577078016f, araw.y * 0.577078016f};
    const f32x2 a04_23 = {araw.z * 0.577078016f, araw.w * 0.577078016f};
    const f32x2 xr01 = {xr4.x, xr4.y}, xr23 = {xr4.z, xr4.w};

    // score = sum a06*z + a04*|z|  (== lrelu(z)*att*log2e), packed pipeline
#define SCOREP(C01, C23, OUT)                                                \
    {                                                                        \
        f32x2 q01 = pk_add(C01, xr01), q23 = pk_add(C23, xr23);              \
        f32x2 pa = pk_mul(q01, a06_01);                                      \
        pa = pk_fma(pk_abs(q01), a04_01, pa);                                \
        pa = pk_fma(q23, a06_23, pa);                                        \
        pa = pk_fma(pk_abs(q23), a04_23, pa);                                \
        OUT = pa[0] + pa[1];                                                 \
    }

    // self edge score = shift m0; contributes exp2(0)=1 and xl4
    f32x2 sl01 = {xl4.x, xl4.y}, sl23 = {xl4.z, xl4.w};
    float p;
    SCOREP(sl01, sl23, p)
    const float m0 = red16(p);

    float s = 1.0f;
    f32x2 a01 = sl01, a23 = sl23;

    int deg = cnt[v];
    if (deg > CAP) deg = CAP;
    const int slot = lane & 31;
    int u_l = (slot < deg) ? tbl[v * CAP + slot] : 0;

    int dmax = deg;
    { int d2 = __shfl_xor(deg, 32); dmax = d2 > dmax ? d2 : dmax; }

    const float* __restrict__ XLh = XL + hc;

    // depth-3 rolling prefetch (per half)
    float4 x0 = make_float4(0,0,0,0), x1 = x0, x2 = x0;
    if (dmax > 0) { int u = __shfl(u_l, 0 + selbase); x0 = *(const float4*)(XLh + (size_t)u * HC); }
    if (dmax > 1) { int u = __shfl(u_l, 1 + selbase); x1 = *(const float4*)(XLh + (size_t)u * HC); }
    if (dmax > 2) { int u = __shfl(u_l, 2 + selbase); x2 = *(const float4*)(XLh + (size_t)u * HC); }

    for (int i = 0; i < dmax; ++i) {
        float4 xc = x0; x0 = x1; x1 = x2;
        int pf = i + 3;
        if (pf < dmax) {
            int u = (pf < 32) ? __shfl(u_l, pf + selbase) : tbl[v * CAP + pf];
            x2 = *(const float4*)(XLh + (size_t)u * HC);
        }
        f32x2 c01 = {xc.x, xc.y}, c23 = {xc.z, xc.w};
        SCOREP(c01, c23, p)
        p = red16(p);
        if (i >= deg) p = -1e30f;               // other half longer -> mask
        float w = exp2f(p - m0);
        s += w;
        f32x2 w2 = {w, w};
        a01 = pk_fma(w2, c01, a01);
        a23 = pk_fma(w2, c23, a23);
    }
#undef SCOREP

    float inv = 1.0f / (s + 1e-16f);
    float ax = a01[0] * inv, ay = a01[1] * inv;
    float az = a23[0] * inv, aw = a23[1] * inv;

    // mean over heads (head1 sits at lane^16 within the half)
    ax += __shfl_xor(ax, 16); ay += __shfl_xor(ay, 16);
    az += __shfl_xor(az, 16); aw += __shfl_xor(aw, 16);
    ax *= 0.5f; ay *= 0.5f; az *= 0.5f; aw *= 0.5f;

    if ((lane & 31) < 16) {
        const float4 b4 = *(const float4*)(bias + 4 * li);
        ax += b4.x; ay += b4.y; az += b4.z; aw += b4.w;
        if (applyGelu) { ax = gelu_f(ax); ay = gelu_f(ay); az = gelu_f(az); aw = gelu_f(aw); }
        *(float4*)(Y + (size_t)v * 64 + 4 * li) = make_float4(ax, ay, az, aw);
    }
}

extern "C" void kernel_launch(void* const* d_in, const int* in_sizes, int n_in,
                              void* d_out, int out_size, void* d_ws, size_t ws_size,
                              hipStream_t stream) {
    const float* X     = (const float*)d_in[0];
    const int*   edges = (const int*)d_in[1];
    const float* Wl    = (const float*)d_in[2];
    const float* bl    = (const float*)d_in[3];
    const float* Wr    = (const float*)d_in[4];
    const float* br    = (const float*)d_in[5];
    const float* att   = (const float*)d_in[6];
    const float* bias  = (const float*)d_in[7];

    char* ws = (char*)d_ws;
    float* XLb = (float*)ws;                                          // N*128 f32
    float* XRb = (float*)(ws + (size_t)N_NODES * HC * 4);             // N*128 f32
    float* Yb  = (float*)(ws + (size_t)N_NODES * HC * 8);             // N*64 f32
    int*   cnt = (int*)(ws + (size_t)N_NODES * HC * 8 + (size_t)N_NODES * 64 * 4);
    int*   tbl = cnt + N_NODES;                                       // N*CAP ints
    unsigned short* WBh  = (unsigned short*)(tbl + (size_t)N_NODES * CAP); // 64 KB
    unsigned short* WBlo = WBh + 32768;                                    // 64 KB

    hipMemsetAsync(cnt, 0, N_NODES * sizeof(int), stream);
    wprep_kernel<<<128, 256, 0, stream>>>(Wl, Wr, WBh, WBlo);

    const int agg_grid = ((N_NODES + 1) / 2 * 64 + 255) / 256;        // 2 nodes/wave

    // layer 0: gemm + scatter fused (matrix/mem pipes vs atomic pipe)
    gemm_scatter_kernel<<<FUSED_BLOCKS, 256, 0, stream>>>(
        X, WBh, WBlo, bl, br, XLb, XRb, edges, cnt, tbl, 1);
    aggregate_kernel<<<agg_grid, 256, 0, stream>>>(XLb, XRb, cnt, tbl, att, bias, Yb, 1);
    // layer 1
    gemm_scatter_kernel<<<GEMM_BLOCKS, 256, 0, stream>>>(
        Yb, WBh + 16384, WBlo + 16384, bl + 128, br + 128, XLb, XRb, edges, cnt, tbl, 0);
    aggregate_kernel<<<agg_grid, 256, 0, stream>>>(XLb, XRb, cnt, tbl, att + 128, bias + 64,
                                                   (float*)d_out, 0);
}